// Round 13
// baseline (995.314 us; speedup 1.0000x reference)
//
#include <hip/hip_runtime.h>
#include <hip/hip_fp16.h>
#include <hip/hip_cooperative_groups.h>

namespace cg = cooperative_groups;

#define NN 20000      // nodes
#define NE 320000     // edges
#define FE 32         // edge feature dim
#define NG 64         // graphs
#define EA_STRIDE 36  // padded LDS row stride (floats)
#define NB 1024       // cooperative grid blocks (upper bound)
#define NT 256

using f16x8 = __attribute__((ext_vector_type(8))) _Float16;
using f32x4 = __attribute__((ext_vector_type(4))) float;

union AFrag {
    f16x8 v;
    __half2 h2[4];
};

struct Params {
    const float* x; const int* ei; const float* ea; const int* batch;
    const float* We; const float* be; const float* Wroot; const float* bconv;
    const float* Wgat; const float* a_src; const float* a_dst; const float* bgat;
    const float* Wfc1; const float* bfc1; const float* Wfc2; const float* bfc2;
    float* out;
    int* deg; float* agg; int* cstart; int* rel_e; int* esrc;
    __half* hpb; float* sc_s; float* sc_d; float* gat; __half* we2t;
    int* wtot; int* woff;
};

static __device__ inline int lbound(const int* b, int key) {
    int lo = 0, hi = NN;
    while (lo < hi) { int mid = (lo + hi) >> 1; if (b[mid] < key) lo = mid + 1; else hi = mid; }
    return lo;
}

// ==================== cooperative mega-kernel ====================
__global__ __launch_bounds__(NT, 4) void mega(Params p) {
    cg::grid_group grid = cg::this_grid();
    __shared__ float smem[4608];             // 4 waves x 2 bufs x 576 floats (msg); reused by poolhead
    const int tid  = threadIdx.x;
    const int lane = tid & 63;
    const int wid  = tid >> 6;
    const int gthread  = blockIdx.x * NT + tid;
    const int nthreads = gridDim.x * NT;
    const int gwave  = gthread >> 6;
    const int nwaves = nthreads >> 6;

    // ---- P0: zero deg+agg, build K-permuted f16 We2t ----
    for (int i = gthread; i < NN; i += nthreads) p.deg[i] = 0;
    for (int i = gthread; i < NN * 16; i += nthreads) p.agg[i] = 0.f;
    for (int i = gthread; i < 16 * 544; i += nthreads) {
        int k = i % 544, m = i / 544;
        float v;
        if (k < 512) {
            int ks = k >> 5, r = k & 31, q = r >> 3, j = r & 7;
            int f = 16 * (q >> 1) + ks;
            int ii = (q & 1) * 8 + j;
            v = p.We[f * 256 + ii * 16 + m];
        } else if (k < 528) v = p.be[(k - 512) * 16 + m];
        else v = 0.f;
        p.we2t[i] = __float2half(v);
    }
    __threadfence();
    grid.sync();

    // ---- P1: dst histogram with relative positions ----
    for (int e = gthread; e < NE; e += nthreads)
        p.rel_e[e] = atomicAdd(&p.deg[p.ei[NE + e]], 1);
    __threadfence();
    grid.sync();

    // ---- P2: scan part 1 — 313 waves, 64 values each ----
    if (gwave < 313) {
        int i = gwave * 64 + lane;
        int v = (i < NN) ? p.deg[i] : 0;
        int inc = v;
        #pragma unroll
        for (int off = 1; off < 64; off <<= 1) {
            int t = __shfl_up(inc, off);
            if (lane >= off) inc += t;
        }
        if (i < NN) p.cstart[i] = inc - v;   // chunk-local exclusive
        if (lane == 63) p.wtot[gwave] = inc; // chunk total
    }
    __threadfence();
    grid.sync();

    // ---- P3: scan part 2 — 1 wave scans 313 chunk totals ----
    if (gwave == 0) {
        int vals[5]; int s = 0;
        #pragma unroll
        for (int k = 0; k < 5; ++k) {
            int idx = lane * 5 + k;
            int v = (idx < 313) ? p.wtot[idx] : 0;
            vals[k] = s; s += v;
        }
        int inc = s;
        #pragma unroll
        for (int off = 1; off < 64; off <<= 1) {
            int t = __shfl_up(inc, off);
            if (lane >= off) inc += t;
        }
        int lexcl = inc - s;
        #pragma unroll
        for (int k = 0; k < 5; ++k) {
            int idx = lane * 5 + k;
            if (idx < 313) p.woff[idx] = lexcl + vals[k];
        }
    }
    __threadfence();
    grid.sync();

    // ---- P4: scan part 3 — add chunk offsets ----
    if (gwave < 313) {
        int off = p.woff[gwave];
        int i = gwave * 64 + lane;
        if (i < NN) p.cstart[i] += off;
    }
    if (gthread == 0) p.cstart[NN] = NE;
    __threadfence();
    grid.sync();

    // ---- P5: NNConv messages, fp16 MFMA, atomic agg + CSR esrc fill ----
    {
        const int m    = lane & 15;
        const int quad = lane >> 4;
        const int pp   = quad >> 1;
        const int xh   = (quad & 1) * 8;
        const int eL   = lane >> 3;
        const int fL   = (lane & 7) * 4;
        float* base = smem + wid * 1152;

        const __half* wt = p.we2t + m * 544 + quad * 8;
        f16x8 bfr[17];
        #pragma unroll
        for (int ks = 0; ks < 17; ++ks)
            bfr[ks] = *(const f16x8*)(wt + ks * 32);

        if (gwave < NE / 16) {   // stage first tile
            const float4* s0 = (const float4*)(p.ea + (long)gwave * 512 + lane * 4);
            float4 v0 = s0[0], v1 = s0[64];
            *(float4*)(base + eL * EA_STRIDE + fL)       = v0;
            *(float4*)(base + (8 + eL) * EA_STRIDE + fL) = v1;
        }
        int buf = 0;
        for (int tile = gwave; tile < NE / 16; tile += nwaves) {
            const int nt = tile + nwaves;
            const bool hasnext = nt < NE / 16;
            float4 nv0, nv1;
            if (hasnext) {
                const float4* sn = (const float4*)(p.ea + (long)nt * 512 + lane * 4);
                nv0 = sn[0]; nv1 = sn[64];
            }
            const int e0 = tile * 16;
            const int r  = e0 + quad * 4 + (m & 3);
            const int s   = p.ei[e0 + m];
            const int d   = p.ei[NE + r];
            const int rel = p.rel_e[r];
            const int src = p.ei[r];

            float xf[8];
            {
                const float4* xr = (const float4*)(p.x + s * 16 + xh);
                float4 a0 = xr[0], a1 = xr[1];
                xf[0]=a0.x; xf[1]=a0.y; xf[2]=a0.z; xf[3]=a0.w;
                xf[4]=a1.x; xf[5]=a1.y; xf[6]=a1.z; xf[7]=a1.w;
            }
            const int c = p.cstart[d] + rel;
            if (m < 4) p.esrc[c] = src;

            const float* bb = base + buf * 576;
            float4 ev[4];
            #pragma unroll
            for (int q = 0; q < 4; ++q)
                ev[q] = *(const float4*)(bb + m * EA_STRIDE + pp * 16 + q * 4);

            __half2 xp[4];
            #pragma unroll
            for (int j = 0; j < 4; ++j)
                xp[j] = __float22half2_rn(make_float2(xf[2*j], xf[2*j+1]));

            f32x4 acc = {0.f, 0.f, 0.f, 0.f};
            #pragma unroll
            for (int ks = 0; ks < 16; ++ks) {
                float evv = ((const float*)ev)[ks];
                __half2 eh = __float2half2_rn(evv);
                AFrag a;
                #pragma unroll
                for (int j = 0; j < 4; ++j) a.h2[j] = __hmul2(eh, xp[j]);
                acc = __builtin_amdgcn_mfma_f32_16x16x32_f16(a.v, bfr[ks], acc, 0, 0, 0);
            }
            {
                AFrag a;
                #pragma unroll
                for (int j = 0; j < 4; ++j) a.h2[j] = xp[j];
                acc = __builtin_amdgcn_mfma_f32_16x16x32_f16(a.v, bfr[16], acc, 0, 0, 0);
            }
            #pragma unroll
            for (int rr = 0; rr < 4; ++rr) {
                int dd = __shfl(d, (quad << 4) | rr);
                atomicAdd(&p.agg[dd * 16 + m], acc[rr]);
            }
            if (hasnext) {
                buf ^= 1;
                float* nb2 = base + buf * 576;
                *(float4*)(nb2 + eL * EA_STRIDE + fL)       = nv0;
                *(float4*)(nb2 + (8 + eL) * EA_STRIDE + fL) = nv1;
            }
        }
    }
    __threadfence();
    grid.sync();

    // ---- P6: node — h, hp, scores ----
    for (int n = gwave; n < NN; n += nwaves) {
        int o = lane & 15;
        float agv = p.agg[n * 16 + o];
        float xv  = p.x[n * 16 + o];
        float acc = p.bconv[o] + agv;
        #pragma unroll
        for (int i = 0; i < 16; ++i) acc += __shfl(xv, i) * p.Wroot[i * 16 + o];
        float hv = fmaxf(acc, 0.f);
        float hpacc = 0.f;
        #pragma unroll
        for (int i = 0; i < 16; ++i) hpacc += __shfl(hv, i) * p.Wgat[i * 64 + lane];
        p.hpb[(long)n * 64 + lane] = __float2half(hpacc);
        float ss = hpacc * p.a_src[lane];
        float sd = hpacc * p.a_dst[lane];
        #pragma unroll
        for (int off = 32; off; off >>= 1) {
            ss += __shfl_xor(ss, off);
            sd += __shfl_xor(sd, off);
        }
        if (lane == 0) { p.sc_s[n] = ss; p.sc_d[n] = sd; }
    }
    __threadfence();
    grid.sync();

    // ---- P7: GAT softmax aggregation (no-max-subtraction: scores are O(few)) ----
    for (int d = gwave; d < NN; d += nwaves) {
        float sdv = p.sc_d[d];
        float es = p.sc_s[d] + sdv;
        es = (es >= 0.f) ? es : 0.2f * es;
        float l0 = __expf(es);
        float acc = l0 * __half2float(p.hpb[(long)d * 64 + lane]);
        float lsum = 0.f;
        int a0 = p.cstart[d], a1 = p.cstart[d + 1];
        for (int bse = a0; bse < a1; bse += 64) {
            int j = bse + lane;
            bool valid = j < a1;
            int s = valid ? p.esrc[j] : 0;
            float sc = valid ? p.sc_s[s] + sdv : 0.f;
            sc = (sc >= 0.f) ? sc : 0.2f * sc;
            float pj = valid ? __expf(sc) : 0.f;
            lsum += pj;
            int cnt = a1 - bse; if (cnt > 64) cnt = 64;
            int k2 = 0;
            for (; k2 + 4 <= cnt; k2 += 4) {
                int   s0 = __shfl(s, k2),     s1 = __shfl(s, k2 + 1);
                int   s2 = __shfl(s, k2 + 2), s3 = __shfl(s, k2 + 3);
                float p0 = __shfl(pj, k2),     p1 = __shfl(pj, k2 + 1);
                float p2 = __shfl(pj, k2 + 2), p3 = __shfl(pj, k2 + 3);
                float h0 = __half2float(p.hpb[(long)s0 * 64 + lane]);
                float h1 = __half2float(p.hpb[(long)s1 * 64 + lane]);
                float h2 = __half2float(p.hpb[(long)s2 * 64 + lane]);
                float h3 = __half2float(p.hpb[(long)s3 * 64 + lane]);
                acc += p0 * h0 + p1 * h1 + p2 * h2 + p3 * h3;
            }
            for (; k2 < cnt; ++k2) {
                int sk = __shfl(s, k2);
                float pk = __shfl(pj, k2);
                acc += pk * __half2float(p.hpb[(long)sk * 64 + lane]);
            }
        }
        #pragma unroll
        for (int off = 32; off; off >>= 1) lsum += __shfl_xor(lsum, off);
        float g = acc / (lsum + l0) + p.bgat[lane];
        p.gat[(long)d * 64 + lane] = fmaxf(g, 0.f);
    }
    __threadfence();
    grid.sync();

    // ---- P8: pool + MLP head; blocks 0..63 ----
    if (blockIdx.x < NG) {
        int g = blockIdx.x;
        float* sd     = smem;        // 256
        float* pooled = smem + 256;  // 64
        float* zl     = smem + 320;  // 128
        int r0 = lbound(p.batch, g);
        int r1 = lbound(p.batch, g + 1);
        int o = tid & 63, gr = tid >> 6;
        float part = 0.f;
        for (int r = r0 + gr; r < r1; r += 4) part += p.gat[(long)r * 64 + o];
        __syncthreads();   // smem was used in P5; ensure all waves done with it
        sd[tid] = part; __syncthreads();
        if (tid < 64) {
            float tot = sd[tid] + sd[64 + tid] + sd[128 + tid] + sd[192 + tid];
            int cnt = r1 - r0;
            pooled[tid] = tot / (float)(cnt > 0 ? cnt : 1);
        }
        __syncthreads();
        if (tid < 128) {
            float a = p.bfc1[tid];
            #pragma unroll 8
            for (int i = 0; i < 64; ++i) a += pooled[i] * p.Wfc1[i * 128 + tid];
            zl[tid] = fmaxf(a, 0.f);
        }
        __syncthreads();
        if (tid < 64) {
            float v = zl[tid] * p.Wfc2[tid] + zl[tid + 64] * p.Wfc2[tid + 64];
            #pragma unroll
            for (int off = 32; off; off >>= 1) v += __shfl_xor(v, off);
            if (tid == 0) p.out[g] = v + p.bfc2[0];
        }
    }
}

// ==================== fallback multi-kernel path (R11, 215 µs, proven) ====================
__global__ void k_histinit(Params p) {
    int e = blockIdx.x * blockDim.x + threadIdx.x;
    if (e < NE) p.rel_e[e] = atomicAdd(&p.deg[p.ei[NE + e]], 1);
    if (e < 16 * 544) {
        int k = e % 544, m = e / 544;
        float v;
        if (k < 512) {
            int ks = k >> 5, r = k & 31, q = r >> 3, j = r & 7;
            int f = 16 * (q >> 1) + ks;
            int i = (q & 1) * 8 + j;
            v = p.We[f * 256 + i * 16 + m];
        } else if (k < 528) v = p.be[(k - 512) * 16 + m];
        else v = 0.f;
        p.we2t[e] = __float2half(v);
    }
}

#define SCAN_K 20
__global__ __launch_bounds__(1024) void k_scan(Params p) {
    __shared__ int wsum[16];
    int t = threadIdx.x;
    int lane = t & 63, wv = t >> 6;
    int base = t * SCAN_K;
    int vals[SCAN_K];
    int s = 0;
    if (base + SCAN_K <= NN) {
        const int4* dv = (const int4*)(p.deg + base);
        int4 b[5];
        #pragma unroll
        for (int q = 0; q < 5; ++q) b[q] = dv[q];
        const int* bb = (const int*)b;
        #pragma unroll
        for (int k = 0; k < SCAN_K; ++k) { vals[k] = s; s += bb[k]; }
    } else {
        #pragma unroll
        for (int k = 0; k < SCAN_K; ++k) vals[k] = 0;
    }
    int isum = s;
    #pragma unroll
    for (int off = 1; off < 64; off <<= 1) {
        int v = __shfl_up(isum, off);
        if (lane >= off) isum += v;
    }
    if (lane == 63) wsum[wv] = isum;
    __syncthreads();
    if (t < 16) {
        int wval = wsum[t];
        #pragma unroll
        for (int off = 1; off < 16; off <<= 1) {
            int v = __shfl_up(wval, off);
            if (t >= off) wval += v;
        }
        wsum[t] = wval;
    }
    __syncthreads();
    int excl = ((wv == 0) ? 0 : wsum[wv - 1]) + (isum - s);
    #pragma unroll
    for (int k = 0; k < SCAN_K; ++k) {
        int i = base + k;
        if (i <= NN) p.cstart[i] = excl + vals[k];
    }
}

#define TPW 4
__global__ __launch_bounds__(256) void k_msg(Params p) {
    __shared__ float lds[4][2][16 * EA_STRIDE];
    const int lane = threadIdx.x & 63;
    const int wid  = threadIdx.x >> 6;
    const int m    = lane & 15;
    const int quad = lane >> 4;
    const int pp   = quad >> 1;
    const int xh   = (quad & 1) * 8;
    const int eL   = lane >> 3;
    const int fL   = (lane & 7) * 4;

    const int gw = blockIdx.x * 4 + wid;
    const int t0 = gw * TPW;

    const __half* wt = p.we2t + m * 544 + quad * 8;
    f16x8 bfr[17];
    #pragma unroll
    for (int ks = 0; ks < 17; ++ks)
        bfr[ks] = *(const f16x8*)(wt + ks * 32);

    {
        const float4* s0 = (const float4*)(p.ea + (long)t0 * 512 + lane * 4);
        float4 v0 = s0[0];
        float4 v1 = s0[64];
        *(float4*)&lds[wid][0][eL * EA_STRIDE + fL]       = v0;
        *(float4*)&lds[wid][0][(8 + eL) * EA_STRIDE + fL] = v1;
    }

    int buf = 0;
    for (int it = 0; it < TPW; ++it) {
        const int tile = t0 + it;
        const int e0   = tile * 16;
        const int r    = e0 + quad * 4 + (m & 3);

        float4 nv0, nv1;
        if (it < TPW - 1) {
            const float4* sn = (const float4*)(p.ea + (long)(tile + 1) * 512 + lane * 4);
            nv0 = sn[0];
            nv1 = sn[64];
        }

        const int s   = p.ei[e0 + m];
        const int d   = p.ei[NE + r];
        const int rel = p.rel_e[r];
        const int src = p.ei[r];

        float xf[8];
        {
            const float4* xr = (const float4*)(p.x + s * 16 + xh);
            float4 a0 = xr[0], a1 = xr[1];
            xf[0]=a0.x; xf[1]=a0.y; xf[2]=a0.z; xf[3]=a0.w;
            xf[4]=a1.x; xf[5]=a1.y; xf[6]=a1.z; xf[7]=a1.w;
        }
        const int c = p.cstart[d] + rel;
        if (m < 4) p.esrc[c] = src;

        float4 ev[4];
        #pragma unroll
        for (int q = 0; q < 4; ++q)
            ev[q] = *(const float4*)&lds[wid][buf][m * EA_STRIDE + pp * 16 + q * 4];

        __half2 xp[4];
        #pragma unroll
        for (int j = 0; j < 4; ++j)
            xp[j] = __float22half2_rn(make_float2(xf[2*j], xf[2*j+1]));

        f32x4 acc = {0.f, 0.f, 0.f, 0.f};
        #pragma unroll
        for (int ks = 0; ks < 16; ++ks) {
            float evv = ((const float*)ev)[ks];
            __half2 eh = __float2half2_rn(evv);
            AFrag a;
            #pragma unroll
            for (int j = 0; j < 4; ++j) a.h2[j] = __hmul2(eh, xp[j]);
            acc = __builtin_amdgcn_mfma_f32_16x16x32_f16(a.v, bfr[ks], acc, 0, 0, 0);
        }
        {
            AFrag a;
            #pragma unroll
            for (int j = 0; j < 4; ++j) a.h2[j] = xp[j];
            acc = __builtin_amdgcn_mfma_f32_16x16x32_f16(a.v, bfr[16], acc, 0, 0, 0);
        }
        #pragma unroll
        for (int rr = 0; rr < 4; ++rr) {
            int dd = __shfl(d, (quad << 4) | rr);
            atomicAdd(&p.agg[dd * 16 + m], acc[rr]);
        }

        if (it < TPW - 1) {
            buf ^= 1;
            *(float4*)&lds[wid][buf][eL * EA_STRIDE + fL]       = nv0;
            *(float4*)&lds[wid][buf][(8 + eL) * EA_STRIDE + fL] = nv1;
        }
    }
}

__global__ __launch_bounds__(256) void k_node(Params p) {
    int n = (blockIdx.x * blockDim.x + threadIdx.x) >> 6;
    int lane = threadIdx.x & 63;
    if (n >= NN) return;
    int o = lane & 15;
    float agv = p.agg[n * 16 + o];
    float xv = p.x[n * 16 + o];
    float acc = p.bconv[o] + agv;
    #pragma unroll
    for (int i = 0; i < 16; ++i) acc += __shfl(xv, i) * p.Wroot[i * 16 + o];
    float hv = fmaxf(acc, 0.f);
    float hpacc = 0.f;
    #pragma unroll
    for (int i = 0; i < 16; ++i) hpacc += __shfl(hv, i) * p.Wgat[i * 64 + lane];
    p.hpb[(long)n * 64 + lane] = __float2half(hpacc);
    float ss = hpacc * p.a_src[lane];
    float sd = hpacc * p.a_dst[lane];
    #pragma unroll
    for (int off = 32; off; off >>= 1) {
        ss += __shfl_xor(ss, off);
        sd += __shfl_xor(sd, off);
    }
    if (lane == 0) { p.sc_s[n] = ss; p.sc_d[n] = sd; }
}

__global__ __launch_bounds__(256) void k_gat(Params p) {
    int d = (blockIdx.x * blockDim.x + threadIdx.x) >> 6;
    int lane = threadIdx.x & 63;
    if (d >= NN) return;
    float sdv = p.sc_d[d];
    float es = p.sc_s[d] + sdv;
    es = (es >= 0.f) ? es : 0.2f * es;
    float l0 = __expf(es);
    float acc = l0 * __half2float(p.hpb[(long)d * 64 + lane]);
    float lsum = 0.f;
    int a0 = p.cstart[d], a1 = p.cstart[d + 1];
    for (int bse = a0; bse < a1; bse += 64) {
        int j = bse + lane;
        bool valid = j < a1;
        int s = valid ? p.esrc[j] : 0;
        float sc = valid ? p.sc_s[s] + sdv : 0.f;
        sc = (sc >= 0.f) ? sc : 0.2f * sc;
        float pj = valid ? __expf(sc) : 0.f;
        lsum += pj;
        int cnt = a1 - bse; if (cnt > 64) cnt = 64;
        int k2 = 0;
        for (; k2 + 4 <= cnt; k2 += 4) {
            int   s0 = __shfl(s, k2),     s1 = __shfl(s, k2 + 1);
            int   s2 = __shfl(s, k2 + 2), s3 = __shfl(s, k2 + 3);
            float p0 = __shfl(pj, k2),     p1 = __shfl(pj, k2 + 1);
            float p2 = __shfl(pj, k2 + 2), p3 = __shfl(pj, k2 + 3);
            float h0 = __half2float(p.hpb[(long)s0 * 64 + lane]);
            float h1 = __half2float(p.hpb[(long)s1 * 64 + lane]);
            float h2 = __half2float(p.hpb[(long)s2 * 64 + lane]);
            float h3 = __half2float(p.hpb[(long)s3 * 64 + lane]);
            acc += p0 * h0 + p1 * h1 + p2 * h2 + p3 * h3;
        }
        for (; k2 < cnt; ++k2) {
            int sk = __shfl(s, k2);
            float pk = __shfl(pj, k2);
            acc += pk * __half2float(p.hpb[(long)sk * 64 + lane]);
        }
    }
    #pragma unroll
    for (int off = 32; off; off >>= 1) lsum += __shfl_xor(lsum, off);
    float g = acc / (lsum + l0) + p.bgat[lane];
    p.gat[(long)d * 64 + lane] = fmaxf(g, 0.f);
}

__global__ __launch_bounds__(256) void k_poolhead(Params p) {
    int g = blockIdx.x;
    int t = threadIdx.x;
    int r0 = lbound(p.batch, g);
    int r1 = lbound(p.batch, g + 1);
    int o = t & 63, gr = t >> 6;
    float part = 0.f;
    for (int r = r0 + gr; r < r1; r += 4) part += p.gat[(long)r * 64 + o];
    __shared__ float sd[256];
    __shared__ float pooled[64];
    __shared__ float zl[128];
    sd[t] = part; __syncthreads();
    if (t < 64) {
        float tot = sd[t] + sd[64 + t] + sd[128 + t] + sd[192 + t];
        int cnt = r1 - r0;
        pooled[t] = tot / (float)(cnt > 0 ? cnt : 1);
    }
    __syncthreads();
    if (t < 128) {
        float a = p.bfc1[t];
        #pragma unroll 8
        for (int i = 0; i < 64; ++i) a += pooled[i] * p.Wfc1[i * 128 + t];
        zl[t] = fmaxf(a, 0.f);
    }
    __syncthreads();
    if (t < 64) {
        float v = zl[t] * p.Wfc2[t] + zl[t + 64] * p.Wfc2[t + 64];
        #pragma unroll
        for (int off = 32; off; off >>= 1) v += __shfl_xor(v, off);
        if (t == 0) p.out[g] = v + p.bfc2[0];
    }
}

extern "C" void kernel_launch(void* const* d_in, const int* in_sizes, int n_in,
                              void* d_out, int out_size, void* d_ws, size_t ws_size,
                              hipStream_t stream) {
    (void)in_sizes; (void)n_in; (void)out_size; (void)ws_size;
    char* w = (char*)d_ws;
    size_t o0  = 0;                            // deg      NN int
    size_t o1  = o0  + (size_t)NN * 4;         // agg      NN*16 f32
    size_t o2  = o1  + (size_t)NN * 16 * 4;    // cstart   (NN+1) int
    size_t o3  = o2  + (size_t)(NN + 1) * 4;   // rel_e    NE int
    size_t o4  = o3  + (size_t)NE * 4;         // esrc     NE int
    size_t o5  = o4  + (size_t)NE * 4;         // hpb      NN*64 f16
    size_t o6  = o5  + (size_t)NN * 64 * 2;    // sc_s     NN f32
    size_t o7  = o6  + (size_t)NN * 4;         // sc_d     NN f32
    size_t o8  = o7  + (size_t)NN * 4;         // gat      NN*64 f32
    size_t o9  = o8  + (size_t)NN * 64 * 4;    // we2t     16*544 f16
    o9 = (o9 + 15) & ~(size_t)15;              // ALIGN FIRST (fixes R11 overlap bug)
    size_t o10 = o9  + (size_t)16 * 544 * 2;   // wtot     320 int
    size_t o11 = o10 + 320 * 4;                // woff     320 int

    Params P;
    P.x     = (const float*)d_in[0];
    P.ei    = (const int*)d_in[1];
    P.ea    = (const float*)d_in[2];
    P.batch = (const int*)d_in[3];
    P.We    = (const float*)d_in[4];
    P.be    = (const float*)d_in[5];
    P.Wroot = (const float*)d_in[6];
    P.bconv = (const float*)d_in[7];
    P.Wgat  = (const float*)d_in[8];
    P.a_src = (const float*)d_in[9];
    P.a_dst = (const float*)d_in[10];
    P.bgat  = (const float*)d_in[11];
    P.Wfc1  = (const float*)d_in[12];
    P.bfc1  = (const float*)d_in[13];
    P.Wfc2  = (const float*)d_in[14];
    P.bfc2  = (const float*)d_in[15];
    P.out   = (float*)d_out;
    P.deg    = (int*)(w + o0);
    P.agg    = (float*)(w + o1);
    P.cstart = (int*)(w + o2);
    P.rel_e  = (int*)(w + o3);
    P.esrc   = (int*)(w + o4);
    P.hpb    = (__half*)(w + o5);
    P.sc_s   = (float*)(w + o6);
    P.sc_d   = (float*)(w + o7);
    P.gat    = (float*)(w + o8);
    P.we2t   = (__half*)(w + o9);
    P.wtot   = (int*)(w + o10);
    P.woff   = (int*)(w + o11);

    // --- try cooperative mega-kernel at the grid the runtime guarantees ---
    int maxBlocksPerCU = 0;
    hipError_t qerr = hipOccupancyMaxActiveBlocksPerMultiprocessor(&maxBlocksPerCU, mega, NT, 0);
    int gridBlocks = (qerr == hipSuccess) ? maxBlocksPerCU * 256 : 0;  // 256 CUs on MI355X
    if (gridBlocks > NB) gridBlocks = NB;

    hipError_t lerr = hipErrorUnknown;
    if (gridBlocks >= 80) {   // P2 needs >=313 waves (80 blocks x 4), P8 needs >=64 blocks
        void* args[] = { (void*)&P };
        lerr = hipLaunchCooperativeKernel((const void*)mega, dim3(gridBlocks), dim3(NT), args, 0, stream);
    }
    if (lerr != hipSuccess) {
        // --- fallback: proven multi-kernel path (R11) ---
        (void)hipMemsetAsync(w, 0, (size_t)NN * 4 + (size_t)NN * 16 * 4, stream); // deg + agg
        k_histinit<<<(NE + 255) / 256, 256, 0, stream>>>(P);
        k_scan<<<1, 1024, 0, stream>>>(P);
        k_msg<<<1250, 256, 0, stream>>>(P);
        k_node<<<(NN + 3) / 4, 256, 0, stream>>>(P);
        k_gat<<<(NN + 3) / 4, 256, 0, stream>>>(P);
        k_poolhead<<<NG, 256, 0, stream>>>(P);
    }
}

// Round 15
// 203.987 us; speedup vs baseline: 4.8793x; 4.8793x over previous
//
#include <hip/hip_runtime.h>
#include <hip/hip_fp16.h>

#define NN 20000      // nodes
#define NE 320000     // edges
#define FE 32         // edge feature dim
#define NG 64         // graphs
#define EA_STRIDE 36  // padded LDS row stride (floats)

using f16x8 = __attribute__((ext_vector_type(8))) _Float16;
using f32x4 = __attribute__((ext_vector_type(4))) float;

union AFrag {
    f16x8 v;
    __half2 h2[4];
};

struct Params {
    const float* x; const int* ei; const float* ea; const int* batch;
    const float* We; const float* be; const float* Wroot; const float* bconv;
    const float* Wgat; const float* a_src; const float* a_dst; const float* bgat;
    const float* Wfc1; const float* bfc1; const float* Wfc2; const float* bfc2;
    float* out;
    int* deg; float* agg; float* pooled; int* cstart; int* rel_e; int* esrc;
    __half* hpb; float* sc_s; float* sc_d; __half* we2t;
};

static __device__ inline int lbound(const int* b, int key) {
    int lo = 0, hi = NN;
    while (lo < hi) { int mid = (lo + hi) >> 1; if (b[mid] < key) lo = mid + 1; else hi = mid; }
    return lo;
}

// ---------------- K0: fused histogram (rel position) + we2t build ----------------
// K permutation: k in [0,512): ks=k>>5, r=k&31, q=r>>3, j=r&7; f=16*(q>>1)+ks; i=(q&1)*8+j
// k in [512,528): bias row i=k-512 ; k in [528,544): zero.
__global__ void k_histinit(Params p) {
    int e = blockIdx.x * blockDim.x + threadIdx.x;
    if (e < NE) p.rel_e[e] = atomicAdd(&p.deg[p.ei[NE + e]], 1);
    if (e < 16 * 544) {
        int k = e % 544, m = e / 544;
        float v;
        if (k < 512) {
            int ks = k >> 5, r = k & 31, q = r >> 3, j = r & 7;
            int f = 16 * (q >> 1) + ks;
            int i = (q & 1) * 8 + j;
            v = p.We[f * 256 + i * 16 + m];
        } else if (k < 528) v = p.be[(k - 512) * 16 + m];
        else v = 0.f;
        p.we2t[e] = __float2half(v);
    }
}

// ---------------- K0b: single-block scan ----------------
#define SCAN_K 20
__global__ __launch_bounds__(1024) void k_scan(Params p) {
    __shared__ int wsum[16];
    int t = threadIdx.x;
    int lane = t & 63, wv = t >> 6;
    int base = t * SCAN_K;
    int vals[SCAN_K];
    int s = 0;
    if (base + SCAN_K <= NN) {
        const int4* dv = (const int4*)(p.deg + base);
        int4 b[5];
        #pragma unroll
        for (int q = 0; q < 5; ++q) b[q] = dv[q];
        const int* bb = (const int*)b;
        #pragma unroll
        for (int k = 0; k < SCAN_K; ++k) { vals[k] = s; s += bb[k]; }
    } else {
        #pragma unroll
        for (int k = 0; k < SCAN_K; ++k) vals[k] = 0;
    }
    int isum = s;
    #pragma unroll
    for (int off = 1; off < 64; off <<= 1) {
        int v = __shfl_up(isum, off);
        if (lane >= off) isum += v;
    }
    if (lane == 63) wsum[wv] = isum;
    __syncthreads();
    if (t < 16) {
        int wval = wsum[t];
        #pragma unroll
        for (int off = 1; off < 16; off <<= 1) {
            int v = __shfl_up(wval, off);
            if (t >= off) wval += v;
        }
        wsum[t] = wval;
    }
    __syncthreads();
    int excl = ((wv == 0) ? 0 : wsum[wv - 1]) + (isum - s);
    #pragma unroll
    for (int k = 0; k < SCAN_K; ++k) {
        int i = base + k;
        if (i <= NN) p.cstart[i] = excl + vals[k];
    }
}

// ---------------- K1: NNConv msg; 4-tile waves, FULL cross-tile software pipeline ----------------
#define TPW 4
__global__ __launch_bounds__(256) void k_msg(Params p) {
    __shared__ float lds[4][2][16 * EA_STRIDE];
    const int lane = threadIdx.x & 63;
    const int wid  = threadIdx.x >> 6;
    const int m    = lane & 15;
    const int quad = lane >> 4;
    const int pp   = quad >> 1;
    const int xh   = (quad & 1) * 8;
    const int eL   = lane >> 3;
    const int fL   = (lane & 7) * 4;

    const int gw = blockIdx.x * 4 + wid;   // 1250 blocks x 4 waves
    const int t0 = gw * TPW;

    // B fragments once per wave
    const __half* wt = p.we2t + m * 544 + quad * 8;
    f16x8 bfr[17];
    #pragma unroll
    for (int ks = 0; ks < 17; ++ks)
        bfr[ks] = *(const f16x8*)(wt + ks * 32);

    // ---- prologue: tile0 scalars + ea + x ----
    int e0 = t0 * 16;
    int r  = e0 + quad * 4 + (m & 3);
    int s   = p.ei[e0 + m];
    int d   = p.ei[NE + r];
    int rel = p.rel_e[r];
    int src = p.ei[r];
    {
        const float4* s0 = (const float4*)(p.ea + (long)t0 * 512 + lane * 4);
        float4 v0 = s0[0], v1 = s0[64];
        *(float4*)&lds[wid][0][eL * EA_STRIDE + fL]       = v0;
        *(float4*)&lds[wid][0][(8 + eL) * EA_STRIDE + fL] = v1;
    }
    float xf[8];
    {
        const float4* xr = (const float4*)(p.x + s * 16 + xh);
        float4 a0 = xr[0], a1 = xr[1];
        xf[0]=a0.x; xf[1]=a0.y; xf[2]=a0.z; xf[3]=a0.w;
        xf[4]=a1.x; xf[5]=a1.y; xf[6]=a1.z; xf[7]=a1.w;
    }

    int buf = 0;
    #pragma unroll
    for (int it = 0; it < TPW; ++it) {
        const int tile = t0 + it;
        const bool hasnext = it < TPW - 1;

        // prefetch next tile's independent loads (ea + scalars) — issue early
        float4 nv0, nv1;
        int s_n = 0, d_n = 0, rel_n = 0, src_n = 0;
        if (hasnext) {
            const float4* sn = (const float4*)(p.ea + (long)(tile + 1) * 512 + lane * 4);
            nv0 = sn[0]; nv1 = sn[64];
            int e0n = (tile + 1) * 16;
            int rn  = e0n + quad * 4 + (m & 3);
            s_n   = p.ei[e0n + m];
            d_n   = p.ei[NE + rn];
            rel_n = p.rel_e[rn];
            src_n = p.ei[rn];
        }

        // CSR slot for this tile (d/rel already resident from prefetch)
        const int c = p.cstart[d] + rel;
        if (m < 4) p.esrc[c] = src;

        // this tile's ea from LDS
        float4 ev[4];
        #pragma unroll
        for (int q = 0; q < 4; ++q)
            ev[q] = *(const float4*)&lds[wid][buf][m * EA_STRIDE + pp * 16 + q * 4];

        __half2 xp[4];
        #pragma unroll
        for (int j = 0; j < 4; ++j)
            xp[j] = __float22half2_rn(make_float2(xf[2*j], xf[2*j+1]));

        f32x4 acc = {0.f, 0.f, 0.f, 0.f};
        #pragma unroll
        for (int ks = 0; ks < 16; ++ks) {
            float evv = ((const float*)ev)[ks];
            __half2 eh = __float2half2_rn(evv);
            AFrag a;
            #pragma unroll
            for (int j = 0; j < 4; ++j) a.h2[j] = __hmul2(eh, xp[j]);
            acc = __builtin_amdgcn_mfma_f32_16x16x32_f16(a.v, bfr[ks], acc, 0, 0, 0);
        }
        {
            AFrag a;
            #pragma unroll
            for (int j = 0; j < 4; ++j) a.h2[j] = xp[j];
            acc = __builtin_amdgcn_mfma_f32_16x16x32_f16(a.v, bfr[16], acc, 0, 0, 0);
        }

        // dependent x gather for next tile — issue AFTER compute (s_n latency covered),
        // BEFORE atomics (x latency covered by atomics + next ds_reads)
        if (hasnext) {
            const float4* xr = (const float4*)(p.x + s_n * 16 + xh);
            float4 a0 = xr[0], a1 = xr[1];
            xf[0]=a0.x; xf[1]=a0.y; xf[2]=a0.z; xf[3]=a0.w;
            xf[4]=a1.x; xf[5]=a1.y; xf[6]=a1.z; xf[7]=a1.w;
        }

        #pragma unroll
        for (int rr = 0; rr < 4; ++rr) {
            int dd = __shfl(d, (quad << 4) | rr);
            atomicAdd(&p.agg[dd * 16 + m], acc[rr]);
        }

        if (hasnext) {
            buf ^= 1;
            *(float4*)&lds[wid][buf][eL * EA_STRIDE + fL]       = nv0;
            *(float4*)&lds[wid][buf][(8 + eL) * EA_STRIDE + fL] = nv1;
            s = s_n; d = d_n; rel = rel_n; src = src_n;
        }
    }
}

// ---------------- K2: node — h, hp, scores ----------------
__global__ __launch_bounds__(256) void k_node(Params p) {
    int n = (blockIdx.x * blockDim.x + threadIdx.x) >> 6;
    int lane = threadIdx.x & 63;
    if (n >= NN) return;
    int o = lane & 15;
    float agv = p.agg[n * 16 + o];
    float xv = p.x[n * 16 + o];
    float acc = p.bconv[o] + agv;
    #pragma unroll
    for (int i = 0; i < 16; ++i) acc += __shfl(xv, i) * p.Wroot[i * 16 + o];
    float hv = fmaxf(acc, 0.f);
    float hpacc = 0.f;
    #pragma unroll
    for (int i = 0; i < 16; ++i) hpacc += __shfl(hv, i) * p.Wgat[i * 64 + lane];
    p.hpb[(long)n * 64 + lane] = __float2half(hpacc);
    float ss = hpacc * p.a_src[lane];
    float sd = hpacc * p.a_dst[lane];
    #pragma unroll
    for (int off = 32; off; off >>= 1) {
        ss += __shfl_xor(ss, off);
        sd += __shfl_xor(sd, off);
    }
    if (lane == 0) { p.sc_s[n] = ss; p.sc_d[n] = sd; }
}

// ---------------- K3: GAT + fused mean-pool accumulation ----------------
__global__ __launch_bounds__(256) void k_gat(Params p) {
    int d = (blockIdx.x * blockDim.x + threadIdx.x) >> 6;
    int lane = threadIdx.x & 63;
    if (d >= NN) return;
    float sdv = p.sc_d[d];
    int gid = p.batch[d];
    float es = p.sc_s[d] + sdv;
    es = (es >= 0.f) ? es : 0.2f * es;
    float l0 = __expf(es);
    float acc = l0 * __half2float(p.hpb[(long)d * 64 + lane]);
    float lsum = 0.f;
    int a0 = p.cstart[d], a1 = p.cstart[d + 1];
    for (int bse = a0; bse < a1; bse += 64) {
        int j = bse + lane;
        bool valid = j < a1;
        int s = valid ? p.esrc[j] : 0;
        float sc = valid ? p.sc_s[s] + sdv : 0.f;
        sc = (sc >= 0.f) ? sc : 0.2f * sc;
        float pj = valid ? __expf(sc) : 0.f;
        lsum += pj;
        int cnt = a1 - bse; if (cnt > 64) cnt = 64;
        int k2 = 0;
        for (; k2 + 4 <= cnt; k2 += 4) {
            int   s0 = __shfl(s, k2),     s1 = __shfl(s, k2 + 1);
            int   s2 = __shfl(s, k2 + 2), s3 = __shfl(s, k2 + 3);
            float p0 = __shfl(pj, k2),     p1 = __shfl(pj, k2 + 1);
            float p2 = __shfl(pj, k2 + 2), p3 = __shfl(pj, k2 + 3);
            float h0 = __half2float(p.hpb[(long)s0 * 64 + lane]);
            float h1 = __half2float(p.hpb[(long)s1 * 64 + lane]);
            float h2 = __half2float(p.hpb[(long)s2 * 64 + lane]);
            float h3 = __half2float(p.hpb[(long)s3 * 64 + lane]);
            acc += p0 * h0 + p1 * h1 + p2 * h2 + p3 * h3;
        }
        for (; k2 < cnt; ++k2) {
            int sk = __shfl(s, k2);
            float pk = __shfl(pj, k2);
            acc += pk * __half2float(p.hpb[(long)sk * 64 + lane]);
        }
    }
    #pragma unroll
    for (int off = 32; off; off >>= 1) lsum += __shfl_xor(lsum, off);
    float g = acc / (lsum + l0) + p.bgat[lane];
    g = fmaxf(g, 0.f);
    atomicAdd(&p.pooled[gid * 64 + lane], g);   // fused mean-pool (sum; /cnt in k_head)
}

// ---------------- K4: MLP head; one block (128 thr) per graph ----------------
__global__ __launch_bounds__(128) void k_head(Params p) {
    int g = blockIdx.x;
    int t = threadIdx.x;
    __shared__ float pl[64];
    __shared__ float zl[128];
    int r0 = lbound(p.batch, g);
    int r1 = lbound(p.batch, g + 1);
    float inv = 1.f / (float)((r1 - r0) > 0 ? (r1 - r0) : 1);
    if (t < 64) pl[t] = p.pooled[g * 64 + t] * inv;
    __syncthreads();
    float a = p.bfc1[t];
    #pragma unroll 8
    for (int i = 0; i < 64; ++i) a += pl[i] * p.Wfc1[i * 128 + t];
    zl[t] = fmaxf(a, 0.f);
    __syncthreads();
    if (t < 64) {
        float v = zl[t] * p.Wfc2[t] + zl[t + 64] * p.Wfc2[t + 64];
        #pragma unroll
        for (int off = 32; off; off >>= 1) v += __shfl_xor(v, off);
        if (t == 0) p.out[g] = v + p.bfc2[0];
    }
}

extern "C" void kernel_launch(void* const* d_in, const int* in_sizes, int n_in,
                              void* d_out, int out_size, void* d_ws, size_t ws_size,
                              hipStream_t stream) {
    (void)in_sizes; (void)n_in; (void)out_size; (void)ws_size;
    char* w = (char*)d_ws;
    size_t o0  = 0;                            // deg      NN int      (zeroed)
    size_t o1  = o0  + (size_t)NN * 4;         // agg      NN*16 f32   (zeroed)
    size_t o2  = o1  + (size_t)NN * 16 * 4;    // pooled   NG*64 f32   (zeroed)
    size_t o3  = o2  + (size_t)NG * 64 * 4;    // cstart   (NN+1) int
    size_t o4  = o3  + (size_t)(NN + 1) * 4;   // rel_e    NE int
    size_t o5  = o4  + (size_t)NE * 4;         // esrc     NE int
    size_t o6  = o5  + (size_t)NE * 4;         // hpb      NN*64 f16
    size_t o7  = o6  + (size_t)NN * 64 * 2;    // sc_s     NN f32
    size_t o8  = o7  + (size_t)NN * 4;         // sc_d     NN f32
    size_t o9  = o8  + (size_t)NN * 4;         // we2t     16*544 f16
    o9 = (o9 + 15) & ~(size_t)15;

    Params P;
    P.x     = (const float*)d_in[0];
    P.ei    = (const int*)d_in[1];
    P.ea    = (const float*)d_in[2];
    P.batch = (const int*)d_in[3];
    P.We    = (const float*)d_in[4];
    P.be    = (const float*)d_in[5];
    P.Wroot = (const float*)d_in[6];
    P.bconv = (const float*)d_in[7];
    P.Wgat  = (const float*)d_in[8];
    P.a_src = (const float*)d_in[9];
    P.a_dst = (const float*)d_in[10];
    P.bgat  = (const float*)d_in[11];
    P.Wfc1  = (const float*)d_in[12];
    P.bfc1  = (const float*)d_in[13];
    P.Wfc2  = (const float*)d_in[14];
    P.bfc2  = (const float*)d_in[15];
    P.out   = (float*)d_out;
    P.deg    = (int*)(w + o0);
    P.agg    = (float*)(w + o1);
    P.pooled = (float*)(w + o2);
    P.cstart = (int*)(w + o3);
    P.rel_e  = (int*)(w + o4);
    P.esrc   = (int*)(w + o5);
    P.hpb    = (__half*)(w + o6);
    P.sc_s   = (float*)(w + o7);
    P.sc_d   = (float*)(w + o8);
    P.we2t   = (__half*)(w + o9);

    (void)hipMemsetAsync(w, 0, o3, stream);   // deg + agg + pooled
    k_histinit<<<(NE + 255) / 256, 256, 0, stream>>>(P);
    k_scan<<<1, 1024, 0, stream>>>(P);
    k_msg<<<1250, 256, 0, stream>>>(P);
    k_node<<<(NN + 3) / 4, 256, 0, stream>>>(P);
    k_gat<<<(NN + 3) / 4, 256, 0, stream>>>(P);
    k_head<<<NG, 128, 0, stream>>>(P);
}